// Round 26
// baseline (192.391 us; speedup 1.0000x reference)
//
#include <hip/hip_runtime.h>
#include <cstdint>

#define BB 4
#define NN 4096
#define CCH 256
#define CAP 256

typedef __attribute__((ext_vector_type(8))) short bf16x8;
typedef __attribute__((ext_vector_type(4))) float f32x4;
typedef __attribute__((ext_vector_type(8))) unsigned short us8;

__device__ __forceinline__ unsigned short bf16rn(float f){
  unsigned u = __float_as_uint(f);
  unsigned r = u + 0x7FFFu + ((u>>16)&1u);
  return (unsigned short)(r>>16);
}
__device__ __forceinline__ float bf16tof(unsigned short h){
  return __uint_as_float(((unsigned)h)<<16);
}
__device__ __forceinline__ void gl_lds16(const void* g, void* l){
  __builtin_amdgcn_global_load_lds(
    (const __attribute__((address_space(1))) void*)g,
    (__attribute__((address_space(3))) void*)l, 16, 0, 0);
}

// ---- prep: split x -> xs [16384][768] bf16 (hi | lo | hi) ----
__global__ __launch_bounds__(256) void prep_x(
    const float* __restrict__ x, unsigned short* __restrict__ xs)
{
  const int stride = gridDim.x * 256;
  for (int idx = blockIdx.x*256 + threadIdx.x; idx < 16384*64; idx += stride){
    const int r = idx >> 6, c4 = (idx & 63) * 4;
    float4 u = *(const float4*)(x + (size_t)r*256 + c4);
    ushort4 h, l;
    h.x=bf16rn(u.x); l.x=bf16rn(u.x - bf16tof(h.x));
    h.y=bf16rn(u.y); l.y=bf16rn(u.y - bf16tof(h.y));
    h.z=bf16rn(u.z); l.z=bf16rn(u.z - bf16tof(h.z));
    h.w=bf16rn(u.w); l.w=bf16rn(u.w - bf16tof(h.w));
    unsigned short* row = xs + (size_t)r*768;
    *(ushort4*)(row + c4)       = h;
    *(ushort4*)(row + 256 + c4) = l;
    *(ushort4*)(row + 512 + c4) = h;
  }
}

// ---- prep: weights -> Wt [512][768] bf16 (hi | hi | lo) ----
__global__ __launch_bounds__(256) void prep_w(
    const float* __restrict__ W1, const float* __restrict__ W2,
    const float* __restrict__ Wa, unsigned short* __restrict__ Wt)
{
  const int n = blockIdx.x;      // 512
  const int k = threadIdx.x;     // 256
  float w = (n < 128) ? W1[(size_t)k*128 + n]
          : (n < 256) ? W2[(size_t)k*128 + (n-128)]
                      : Wa[(size_t)k*256 + (n-256)];
  unsigned short h = bf16rn(w);
  unsigned short l = bf16rn(w - bf16tof(h));
  unsigned short* row = Wt + (size_t)n*768;
  row[k] = h; row[256+k] = h; row[512+k] = l;
}

// ---- fused projection GEMM: 64x64 tiles (8 bx x 256 by), XCD-swizzled ----
__global__ __launch_bounds__(256) void proj_mfma(
    const unsigned short* __restrict__ xs, const unsigned short* __restrict__ Wt,
    const float* __restrict__ b1, const float* __restrict__ a1,
    const float* __restrict__ b2, const float* __restrict__ a2,
    const float* __restrict__ ba, const float* __restrict__ aa,
    unsigned short* __restrict__ e1x, unsigned short* __restrict__ e2x,
    float* __restrict__ Vf)
{
  __shared__ __align__(16) short As[64*64];   // 8 KB
  __shared__ __align__(16) short Bs[64*64];   // 8 KB
  const int t = threadIdx.x;
  const int bid = blockIdx.y * 8 + blockIdx.x;
  const int W = (bid & 7) * 256 + (bid >> 3);
  const int bx = W & 7, by = W >> 3;
  const int m0 = by*64;
  const int wid = t>>6, lane = t&63;
  const int wr = wid>>1, wc = wid&1;
  const int fr = lane&15, fq = lane>>4;
  const int r32 = t>>3, seg = t&7;

  const bool isV = bx >= 4;
  const int wrow = isV ? (256 + (bx-4)*64) : ((bx>>1)*128 + (bx&1)*64);
  const unsigned short* ap = xs + (size_t)m0*768;
  const unsigned short* bp = Wt + (size_t)wrow*768;

  f32x4 acc[2][2];
#pragma unroll
  for (int m=0;m<2;m++)
#pragma unroll
    for (int n=0;n<2;n++) acc[m][n] = (f32x4){0.f,0.f,0.f,0.f};

  const int nsteps = isV ? 4 : 12;
  for (int s=0;s<nsteps;s++){
    const int kk = s*64;
#pragma unroll
    for (int i=0;i<2;i++){
      const int rowL = r32 + i*32;
      const int sw = (seg ^ (rowL & 7)) * 8;
      gl_lds16(ap + (size_t)rowL*768 + kk + sw, &As[rowL*64 + seg*8]);
      gl_lds16(bp + (size_t)rowL*768 + kk + sw, &Bs[rowL*64 + seg*8]);
    }
    __syncthreads();
    bf16x8 af[2][2], bf[2][2];
#pragma unroll
    for (int m=0;m<2;m++){
      const int ar_ = wr*32 + m*16 + fr;
#pragma unroll
      for (int ks=0;ks<2;ks++)
        af[m][ks] = *(const bf16x8*)&As[ar_*64 + (((ks*4+fq) ^ (ar_&7))*8)];
    }
#pragma unroll
    for (int n=0;n<2;n++){
      const int br_ = wc*32 + n*16 + fr;
#pragma unroll
      for (int ks=0;ks<2;ks++)
        bf[n][ks] = *(const bf16x8*)&Bs[br_*64 + (((ks*4+fq) ^ (br_&7))*8)];
    }
#pragma unroll
    for (int m=0;m<2;m++)
#pragma unroll
      for (int n=0;n<2;n++)
#pragma unroll
        for (int ks=0;ks<2;ks++)
          acc[m][n] = __builtin_amdgcn_mfma_f32_16x16x32_bf16(af[m][ks], bf[n][ks], acc[m][n], 0,0,0);
    __syncthreads();
  }

  if (!isV){
    const int which = bx >> 1;
    const int n0 = (bx & 1) * 64;
    const float* bb = which ? b2 : b1;
    const float al = which ? a2[0] : a1[0];
#pragma unroll
    for (int m=0;m<2;m++){
#pragma unroll
      for (int n=0;n<2;n++){
        const int c = n0 + wc*32 + n*16 + fr;
        const float bias = bb[c];
#pragma unroll
        for (int reg=0;reg<4;reg++){
          const size_t r = (size_t)(m0 + wr*32 + m*16 + fq*4 + reg);
          float u = acc[m][n][reg] + bias;
          u = u >= 0.f ? u : al*u;
          unsigned short h = bf16rn(u);
          if (which == 0){         // e1x: [h | l]
            e1x[r*256 + c] = h;
            e1x[r*256 + 128 + c] = bf16rn(u - bf16tof(h));
          } else {                 // e2x: [h]
            e2x[r*128 + c] = h;
          }
        }
      }
    }
  } else {
    const int n0 = (bx - 4) * 64;
    const float al = aa[0];
#pragma unroll
    for (int m=0;m<2;m++){
#pragma unroll
      for (int n=0;n<2;n++){
        const int c = n0 + wc*32 + n*16 + fr;
        const float bias = ba[c];
#pragma unroll
        for (int reg=0;reg<4;reg++){
          const size_t r = (size_t)(m0 + wr*32 + m*16 + fq*4 + reg);
          float u = acc[m][n][reg] + bias;
          Vf[r*CCH + c] = u >= 0.f ? u : al*u;
        }
      }
    }
  }
}

// ---- QK^T 128x128: (A_h+A_l)·B, 2 K-steps; emits candidate slots (no S) ----
// Slot (16B): 4 x u32 = (col<<16) | fp16(s - tilemax); invalid = 0xFFFF0000.
// Ballot-based deterministic extraction (no atomics). cnt>4 => spv2 recomputes.
__global__ __launch_bounds__(256) void qk_mfma(
    const unsigned short* __restrict__ e1base, const unsigned short* __restrict__ e2base,
    uint4* __restrict__ Cs, unsigned char* __restrict__ Ccnt,
    float* __restrict__ Mg)
{
  __shared__ __align__(16) short Ah[128*64];   // 16 KB (scratch after loop)
  __shared__ __align__(16) short Al[128*64];   // 16 KB
  __shared__ __align__(16) short Bsh[128*64];  // 16 KB
  const int t = threadIdx.x;
  const int bid = (blockIdx.z * 32 + blockIdx.y) * 32 + blockIdx.x;
  const int W = (bid & 7) * 512 + (bid >> 3);
  const int bx = W & 31, by = (W >> 5) & 31, z = W >> 10;
  const int m0 = by*128, n0 = bx*128;
  const int wid = t>>6, lane = t&63;
  const int wr = wid>>1, wc = wid&1;
  const int fr = lane&15, fq = lane>>4;
  const int r32 = t>>3, seg = t&7;

  const unsigned short* ap = e1base + (size_t)z*NN*256 + (size_t)m0*256;
  const unsigned short* bp = e2base + (size_t)z*NN*128 + (size_t)n0*128;

  f32x4 acc[4][4];
#pragma unroll
  for (int m=0;m<4;m++)
#pragma unroll
    for (int n=0;n<4;n++) acc[m][n] = (f32x4){0.f,0.f,0.f,0.f};

#pragma unroll
  for (int s=0;s<2;s++){
    const int kk = s*64;
#pragma unroll
    for (int i=0;i<4;i++){
      const int rowL = r32 + i*32;
      const int sw = (seg ^ (rowL & 7)) * 8;
      gl_lds16(ap + (size_t)rowL*256 + kk + sw,       &Ah[rowL*64 + seg*8]);
      gl_lds16(ap + (size_t)rowL*256 + 128 + kk + sw, &Al[rowL*64 + seg*8]);
      gl_lds16(bp + (size_t)rowL*128 + kk + sw,       &Bsh[rowL*64 + seg*8]);
    }
    __syncthreads();
#pragma unroll
    for (int ks=0;ks<2;ks++){
      bf16x8 bf[4];
#pragma unroll
      for (int n=0;n<4;n++){
        const int br_ = wc*64 + n*16 + fr;
        bf[n] = *(const bf16x8*)&Bsh[br_*64 + (((ks*4+fq) ^ (br_&7))*8)];
      }
#pragma unroll
      for (int m=0;m<4;m++){
        const int ar_ = wr*64 + m*16 + fr;
        const int off = ar_*64 + (((ks*4+fq) ^ (ar_&7))*8);
        const bf16x8 ah = *(const bf16x8*)&Ah[off];
        const bf16x8 al = *(const bf16x8*)&Al[off];
#pragma unroll
        for (int n=0;n<4;n++){
          acc[m][n] = __builtin_amdgcn_mfma_f32_16x16x32_bf16(ah, bf[n], acc[m][n], 0,0,0);
          acc[m][n] = __builtin_amdgcn_mfma_f32_16x16x32_bf16(al, bf[n], acc[m][n], 0,0,0);
        }
      }
    }
    __syncthreads();
  }

  // scratch in Ah: Mh2[256] | Mc[128] | cand[512 u32] | ccnt[128]
  float*    Fs   = (float*)Ah;
  float*    Mh2  = Fs;
  float*    Mc   = Fs + 256;
  unsigned* cand = (unsigned*)(Fs + 384);
  int*      ccnt = (int*)(Fs + 896);

  // half-tile maxes + init cand slots
#pragma unroll
  for (int m=0;m<4;m++){
#pragma unroll
    for (int reg=0;reg<4;reg++){
      float mm = fmaxf(fmaxf(acc[m][0][reg],acc[m][1][reg]),
                       fmaxf(acc[m][2][reg],acc[m][3][reg]));
#pragma unroll
      for (int o=1;o<16;o<<=1) mm = fmaxf(mm, __shfl_xor(mm, o));
      if (fr == 0) Mh2[(wr*64 + m*16 + fq*4 + reg)*2 + wc] = mm;
    }
  }
  cand[t] = 0xFFFF0000u; cand[t+256] = 0xFFFF0000u;
  __syncthreads();
  if (t < 128){
    const float vmax = fmaxf(Mh2[t*2+0], Mh2[t*2+1]);
    Mc[t] = vmax;
    Mg[((size_t)z*NN + m0 + t)*32 + bx] = vmax;
  }
  __syncthreads();

  // Phase A: wc==0 waves extract (ballot-compact, deterministic, no atomics)
  if (wc == 0){
#pragma unroll
    for (int m=0;m<4;m++){
#pragma unroll
      for (int reg=0;reg<4;reg++){
        const int rl = wr*64 + m*16 + fq*4 + reg;
        const float tmv = Mc[rl];
        const float thr = tmv - 1.0f;
        int cnt = 0;
#pragma unroll
        for (int n=0;n<4;n++){
          const float val = acc[m][n][reg];
          const bool cond = val > thr;
          unsigned long long b = __ballot(cond);
          const unsigned s16 = (unsigned)(b >> (fq*16)) & 0xFFFFu;
          const int pos = cnt + __popc(s16 & ((1u<<fr)-1u));
          if (cond && pos < 4){
            const unsigned short d =
              __builtin_bit_cast(unsigned short, (_Float16)(val - tmv));
            cand[rl*4 + pos] = ((unsigned)(n*16 + fr) << 16) | (unsigned)d;
          }
          cnt += __popc(s16);
        }
        if (fr == 0) ccnt[rl] = cnt;
      }
    }
  }
  __syncthreads();
  // Phase B: wc==1 waves append
  if (wc == 1){
#pragma unroll
    for (int m=0;m<4;m++){
#pragma unroll
      for (int reg=0;reg<4;reg++){
        const int rl = wr*64 + m*16 + fq*4 + reg;
        const float tmv = Mc[rl];
        const float thr = tmv - 1.0f;
        int cnt = ccnt[rl];
#pragma unroll
        for (int n=0;n<4;n++){
          const float val = acc[m][n][reg];
          const bool cond = val > thr;
          unsigned long long b = __ballot(cond);
          const unsigned s16 = (unsigned)(b >> (fq*16)) & 0xFFFFu;
          const int pos = cnt + __popc(s16 & ((1u<<fr)-1u));
          if (cond && pos < 4){
            const unsigned short d =
              __builtin_bit_cast(unsigned short, (_Float16)(val - tmv));
            cand[rl*4 + pos] = ((unsigned)(64 + n*16 + fr) << 16) | (unsigned)d;
          }
          cnt += __popc(s16);
        }
        if (fr == 0) ccnt[rl] = cnt;
      }
    }
  }
  __syncthreads();
  if (t < 128){
    const size_t si = ((size_t)(z*NN + m0 + t))*32 + bx;
    Cs[si] = make_uint4(cand[t*4+0], cand[t*4+1], cand[t*4+2], cand[t*4+3]);
    const int c = ccnt[t];
    Ccnt[si] = (unsigned char)(c > 255 ? 255 : c);
  }
}

// ---- selective sparsemax + sparse PV over candidate slots ----
__global__ __launch_bounds__(256) void spv2(
    const uint4* __restrict__ Cs, const unsigned char* __restrict__ Ccnt,
    const float* __restrict__ Mg,
    const unsigned short* __restrict__ e1x, const unsigned short* __restrict__ e2x,
    const float* __restrict__ V, const float* __restrict__ xr,
    float* __restrict__ out)
{
  __shared__ float av[4][128];
  __shared__ float lv[4][CAP];
  __shared__ int   li[4][CAP];
  __shared__ int   hlist[4][32];
  const int t = threadIdx.x, wid = t>>6, lane = t&63;
  const int row = blockIdx.x*4 + wid;      // 0..16383
  const int z = row >> 12;
  const float* mrow = Mg + (size_t)row*32;

  // stage av = h + l of e1 row (for rare recompute paths)
  {
    const unsigned* src = (const unsigned*)(e1x + (size_t)row*256);
    const unsigned u0 = src[lane];
    const unsigned u1 = src[64 + lane];
    av[wid][lane*2]   = bf16tof((unsigned short)(u0 & 0xFFFFu))
                      + bf16tof((unsigned short)(u1 & 0xFFFFu));
    av[wid][lane*2+1] = bf16tof((unsigned short)(u0 >> 16))
                      + bf16tof((unsigned short)(u1 >> 16));
  }

  // row max + hot-tile list
  float mv = (lane < 32) ? mrow[lane] : -1e30f;
#pragma unroll
  for (int o=32;o;o>>=1) mv = fmaxf(mv, __shfl_xor(mv, o));
  const float th = mv - 1.0f;
  const bool q = (lane < 32) && (mrow[lane] > th);
  const unsigned long long qm = __ballot(q);
  const int nh = __popcll(qm);
  if (q) hlist[wid][__popcll(qm & ((1ULL<<lane)-1ULL))] = lane;
  __syncthreads();

  const unsigned short* e2b = e2x + (size_t)z*NN*128;
  const float* a = av[wid];

  // lane handles one hot tile; decode slot (sorted for determinism)
  const int tile_l = (lane < nh) ? hlist[wid][lane] : -1;
  int cnt = 0;
  unsigned s0=0xFFFF0000u, s1=0xFFFF0000u, s2=0xFFFF0000u, s3=0xFFFF0000u;
  if (tile_l >= 0){
    const size_t si = (size_t)row*32 + tile_l;
    cnt = Ccnt[si];
    const uint4 sl = Cs[si];
    s0=sl.x; s1=sl.y; s2=sl.z; s3=sl.w;
  }
  { unsigned tu;
    if (s0>s1){tu=s0;s0=s1;s1=tu;} if (s2>s3){tu=s2;s2=s3;s3=tu;}
    if (s0>s2){tu=s0;s0=s2;s2=tu;} if (s1>s3){tu=s1;s1=s3;s3=tu;}
    if (s1>s2){tu=s1;s1=s2;s2=tu;} }
  const unsigned se[4] = {s0,s1,s2,s3};
  const bool usable = (tile_l >= 0) && (cnt <= 4);
  const float tmv = (tile_l >= 0) ? mrow[tile_l] : 0.f;

  int cntw = 0;
#pragma unroll
  for (int j=0;j<4;j++){
    const unsigned e = se[j];
    const int col = e >> 16;
    const float sv = tmv + (float)__builtin_bit_cast(_Float16, (unsigned short)(e & 0xFFFFu));
    const bool valid = usable && (col != 0xFFFF) && (sv > th);
    unsigned long long b = __ballot(valid);
    const int pos = cntw + __popcll(b & ((1ULL<<lane)-1ULL));
    if (valid && pos < CAP){ lv[wid][pos] = sv; li[wid][pos] = tile_l*128 + col; }
    cntw += __popcll(b);
  }
  // overflow tiles (cnt>4): whole-wave exact recompute of the tile
  {
    unsigned long long om = __ballot((tile_l >= 0) && (cnt > 4));
    while (om){
      const int lp = __ffsll(om) - 1; om &= om - 1;
      const int tile = hlist[wid][lp];
      const unsigned short* p0 = e2b + (size_t)(tile*128 + lane*2)*128;
      float sa = 0.f, sb = 0.f;
#pragma unroll
      for (int kc=0;kc<16;kc++){
        const us8 h0 = *(const us8*)(p0 + kc*8);
        const us8 h1 = *(const us8*)(p0 + 128 + kc*8);
#pragma unroll
        for (int j=0;j<8;j++){
          const float aa_ = a[kc*8+j];
          sa = fmaf(aa_, bf16tof(h0[j]), sa);
          sb = fmaf(aa_, bf16tof(h1[j]), sb);
        }
      }
      const bool c0 = sa > th;
      unsigned long long b0 = __ballot(c0);
      int pa = cntw + __popcll(b0 & ((1ULL<<lane)-1ULL));
      if (c0 && pa < CAP){ lv[wid][pa] = sa; li[wid][pa] = tile*128 + lane*2; }
      cntw += __popcll(b0);
      const bool c1 = sb > th;
      unsigned long long b1 = __ballot(c1);
      int pb = cntw + __popcll(b1 & ((1ULL<<lane)-1ULL));
      if (c1 && pb < CAP){ lv[wid][pb] = sb; li[wid][pb] = tile*128 + lane*2 + 1; }
      cntw += __popcll(b1);
    }
  }
  const bool ovf = cntw > CAP;

  float tau = th;
  int k = -1;
  if (!ovf){
    float ev[4]; int ei[4];
#pragma unroll
    for (int j=0;j<4;j++){
      const int qq = j*64 + lane;
      if (qq < cntw){ ev[j] = lv[wid][qq]; ei[j] = li[wid][qq]; }
      else          { ev[j] = -1e30f; ei[j] = 0; }
    }
    int prev = -1;
    for (int it=0; it<64; ++it){
      float s = 0.f; int kk = 0;
#pragma unroll
      for (int j=0;j<4;j++) if (ev[j] > tau){ s += ev[j]; kk++; }
#pragma unroll
      for (int o=32;o;o>>=1){ s += __shfl_xor(s,o); kk += __shfl_xor(kk,o); }
      const float tn = (s - 1.f)/(float)kk;
      if (kk == prev) break;
      prev = kk; tau = tn;
    }
    int k2 = 0;
#pragma unroll
    for (int j=0;j<4;j++){
      const int qq = j*64 + lane;
      const float p = ev[j] - tau;
      const bool nz = (qq < cntw) && (p > 0.f);
      unsigned long long b = __ballot(nz);
      const int pos = k2 + __popcll(b & ((1ULL<<lane)-1ULL));
      if (nz){ lv[wid][pos] = p; li[wid][pos] = ei[j]; }
      k2 += __popcll(b);
    }
    k = k2;
  } else {
    // exact fallback: streaming Michelot recomputing hot tiles
    int prev = -1;
    for (int it=0; it<64; ++it){
      float s = 0.f; int kk = 0;
      unsigned long long rem = qm;
      while (rem){
        const int tile = __ffsll(rem) - 1; rem &= rem - 1;
        const unsigned short* p0 = e2b + (size_t)(tile*128 + lane*2)*128;
        float sa = 0.f, sb = 0.f;
#pragma unroll
        for (int kc=0;kc<16;kc++){
          const us8 h0 = *(const us8*)(p0 + kc*8);
          const us8 h1 = *(const us8*)(p0 + 128 + kc*8);
#pragma unroll
          for (int j=0;j<8;j++){
            const float aa_ = a[kc*8+j];
            sa = fmaf(aa_, bf16tof(h0[j]), sa);
            sb = fmaf(aa_, bf16tof(h1[j]), sb);
          }
        }
        if (sa > tau){ s += sa; kk++; }
        if (sb > tau){ s += sb; kk++; }
      }
#pragma unroll
      for (int o=32;o;o>>=1){ s += __shfl_xor(s,o); kk += __shfl_xor(kk,o); }
      const float tn = (s - 1.f)/(float)kk;
      if (kk == prev) break;
      prev = kk; tau = tn;
    }
  }

  // sparse PV + residual
  const float* Vb = V + ((size_t)z << 12) * CCH;
  float4 aacc = *(const float4*)&xr[(size_t)row*CCH + lane*4];
  if (k >= 0){
    for (int qq=0; qq<k; ++qq){
      const float p = lv[wid][qq];
      const int ix = li[wid][qq];
      const float4 vv = *(const float4*)&Vb[(size_t)ix*CCH + lane*4];
      aacc.x = fmaf(p, vv.x, aacc.x); aacc.y = fmaf(p, vv.y, aacc.y);
      aacc.z = fmaf(p, vv.z, aacc.z); aacc.w = fmaf(p, vv.w, aacc.w);
    }
  } else {
    unsigned long long rem = qm;
    while (rem){
      const int tile = __ffsll(rem) - 1; rem &= rem - 1;
      const unsigned short* p0 = e2b + (size_t)(tile*128 + lane*2)*128;
      float sa = 0.f, sb = 0.f;
#pragma unroll
      for (int kc=0;kc<16;kc++){
        const us8 h0 = *(const us8*)(p0 + kc*8);
        const us8 h1 = *(const us8*)(p0 + 128 + kc*8);
#pragma unroll
        for (int j=0;j<8;j++){
          const float aa_ = a[kc*8+j];
          sa = fmaf(aa_, bf16tof(h0[j]), sa);
          sb = fmaf(aa_, bf16tof(h1[j]), sb);
        }
      }
      int base = 0;
      const bool c0 = sa > tau;
      unsigned long long b0 = __ballot(c0);
      int pa = __popcll(b0 & ((1ULL<<lane)-1ULL));
      if (c0){ lv[wid][pa] = sa - tau; li[wid][pa] = tile*128 + lane*2; }
      base = __popcll(b0);
      const bool c1 = sb > tau;
      unsigned long long b1 = __ballot(c1);
      int pb = base + __popcll(b1 & ((1ULL<<lane)-1ULL));
      if (c1){ lv[wid][pb] = sb - tau; li[wid][pb] = tile*128 + lane*2 + 1; }
      base += __popcll(b1);
      for (int qq=0; qq<base; ++qq){
        const float p = lv[wid][qq];
        const int ix = li[wid][qq];
        const float4 vv = *(const float4*)&Vb[(size_t)ix*CCH + lane*4];
        aacc.x = fmaf(p, vv.x, aacc.x); aacc.y = fmaf(p, vv.y, aacc.y);
        aacc.z = fmaf(p, vv.z, aacc.z); aacc.w = fmaf(p, vv.w, aacc.w);
      }
    }
  }
  *(float4*)&out[(size_t)row*CCH + lane*4] = aacc;
}

extern "C" void kernel_launch(void* const* d_in, const int* in_sizes, int n_in,
                              void* d_out, int out_size, void* d_ws, size_t ws_size,
                              hipStream_t stream) {
  const float* x  = (const float*)d_in[0];
  const float* W1 = (const float*)d_in[1];
  const float* b1 = (const float*)d_in[2];
  const float* a1 = (const float*)d_in[3];
  const float* W2 = (const float*)d_in[4];
  const float* b2 = (const float*)d_in[5];
  const float* a2 = (const float*)d_in[6];
  const float* Wa = (const float*)d_in[7];
  const float* ba = (const float*)d_in[8];
  const float* aa = (const float*)d_in[9];
  float* out = (float*)d_out;

  // ws: xs 25.2MB | Wt 0.8 | e1x 8.4 | e2x 4.2 | V 16.8 | Cs 8.4 | Ccnt 0.5  (~64MB)
  unsigned short* xs  = (unsigned short*)d_ws;
  unsigned short* Wt  = xs  + (size_t)16384*768;
  unsigned short* e1x = Wt  + (size_t)512*768;
  unsigned short* e2x = e1x + (size_t)16384*256;
  float* Vf = (float*)(e2x + (size_t)16384*128);
  uint4* Cs = (uint4*)(Vf + (size_t)BB*NN*CCH);
  unsigned char* Ccnt = (unsigned char*)(Cs + (size_t)16384*32);
  float* Mg = (float*)xs;   // xs dead after proj_mfma; tile maxes 2MB

  dim3 blk(256);
  prep_x<<<dim3(2048,1,1), blk, 0, stream>>>(x, xs);
  prep_w<<<dim3(512,1,1), blk, 0, stream>>>(W1, W2, Wa, Wt);
  proj_mfma<<<dim3(8,256,1), blk, 0, stream>>>(xs, Wt, b1,a1, b2,a2, ba,aa,
                                               e1x, e2x, Vf);
  qk_mfma<<<dim3(32,32,4), blk, 0, stream>>>(e1x, e2x, Cs, Ccnt, Mg);
  spv2<<<dim3(4096,1,1), blk, 0, stream>>>(Cs, Ccnt, Mg, e1x, e2x, Vf, x, out);
}

// Round 27
// 115.453 us; speedup vs baseline: 1.6664x; 1.6664x over previous
//
#include <hip/hip_runtime.h>
#include <cstdint>

#define BB 4
#define NN 4096
#define CCH 256
#define CAP 256

typedef __attribute__((ext_vector_type(8))) short bf16x8;
typedef __attribute__((ext_vector_type(4))) float f32x4;

__device__ __forceinline__ unsigned short bf16rn(float f){
  unsigned u = __float_as_uint(f);
  unsigned r = u + 0x7FFFu + ((u>>16)&1u);
  return (unsigned short)(r>>16);
}
__device__ __forceinline__ float bf16tof(unsigned short h){
  return __uint_as_float(((unsigned)h)<<16);
}
__device__ __forceinline__ void gl_lds16(const void* g, void* l){
  __builtin_amdgcn_global_load_lds(
    (const __attribute__((address_space(1))) void*)g,
    (__attribute__((address_space(3))) void*)l, 16, 0, 0);
}
__device__ __forceinline__ unsigned pkh2(float a, float b){
  unsigned short u0 = __builtin_bit_cast(unsigned short, (_Float16)a);
  unsigned short u1 = __builtin_bit_cast(unsigned short, (_Float16)b);
  return (unsigned)u0 | ((unsigned)u1 << 16);
}

// ---- prep: split x -> xs [16384][768] bf16 (hi | lo | hi) ----
__global__ __launch_bounds__(256) void prep_x(
    const float* __restrict__ x, unsigned short* __restrict__ xs)
{
  const int stride = gridDim.x * 256;
  for (int idx = blockIdx.x*256 + threadIdx.x; idx < 16384*64; idx += stride){
    const int r = idx >> 6, c4 = (idx & 63) * 4;
    float4 u = *(const float4*)(x + (size_t)r*256 + c4);
    ushort4 h, l;
    h.x=bf16rn(u.x); l.x=bf16rn(u.x - bf16tof(h.x));
    h.y=bf16rn(u.y); l.y=bf16rn(u.y - bf16tof(h.y));
    h.z=bf16rn(u.z); l.z=bf16rn(u.z - bf16tof(h.z));
    h.w=bf16rn(u.w); l.w=bf16rn(u.w - bf16tof(h.w));
    unsigned short* row = xs + (size_t)r*768;
    *(ushort4*)(row + c4)       = h;
    *(ushort4*)(row + 256 + c4) = l;
    *(ushort4*)(row + 512 + c4) = h;
  }
}

// ---- prep: weights -> Wt [512][768] bf16 (hi | hi | lo) ----
__global__ __launch_bounds__(256) void prep_w(
    const float* __restrict__ W1, const float* __restrict__ W2,
    const float* __restrict__ Wa, unsigned short* __restrict__ Wt)
{
  const int n = blockIdx.x;      // 512
  const int k = threadIdx.x;     // 256
  float w = (n < 128) ? W1[(size_t)k*128 + n]
          : (n < 256) ? W2[(size_t)k*128 + (n-128)]
                      : Wa[(size_t)k*256 + (n-256)];
  unsigned short h = bf16rn(w);
  unsigned short l = bf16rn(w - bf16tof(h));
  unsigned short* row = Wt + (size_t)n*768;
  row[k] = h; row[256+k] = h; row[512+k] = l;
}

// ---- fused projection GEMM: 64x64 tiles (8 bx x 256 by), XCD-swizzled ----
__global__ __launch_bounds__(256) void proj_mfma(
    const unsigned short* __restrict__ xs, const unsigned short* __restrict__ Wt,
    const float* __restrict__ b1, const float* __restrict__ a1,
    const float* __restrict__ b2, const float* __restrict__ a2,
    const float* __restrict__ ba, const float* __restrict__ aa,
    unsigned short* __restrict__ e1x, unsigned short* __restrict__ e2x,
    float* __restrict__ Vf)
{
  __shared__ __align__(16) short As[64*64];   // 8 KB
  __shared__ __align__(16) short Bs[64*64];   // 8 KB
  const int t = threadIdx.x;
  const int bid = blockIdx.y * 8 + blockIdx.x;
  const int W = (bid & 7) * 256 + (bid >> 3);
  const int bx = W & 7, by = W >> 3;
  const int m0 = by*64;
  const int wid = t>>6, lane = t&63;
  const int wr = wid>>1, wc = wid&1;
  const int fr = lane&15, fq = lane>>4;
  const int r32 = t>>3, seg = t&7;

  const bool isV = bx >= 4;
  const int wrow = isV ? (256 + (bx-4)*64) : ((bx>>1)*128 + (bx&1)*64);
  const unsigned short* ap = xs + (size_t)m0*768;
  const unsigned short* bp = Wt + (size_t)wrow*768;

  f32x4 acc[2][2];
#pragma unroll
  for (int m=0;m<2;m++)
#pragma unroll
    for (int n=0;n<2;n++) acc[m][n] = (f32x4){0.f,0.f,0.f,0.f};

  const int nsteps = isV ? 4 : 12;
  for (int s=0;s<nsteps;s++){
    const int kk = s*64;
#pragma unroll
    for (int i=0;i<2;i++){
      const int rowL = r32 + i*32;
      const int sw = (seg ^ (rowL & 7)) * 8;
      gl_lds16(ap + (size_t)rowL*768 + kk + sw, &As[rowL*64 + seg*8]);
      gl_lds16(bp + (size_t)rowL*768 + kk + sw, &Bs[rowL*64 + seg*8]);
    }
    __syncthreads();
    bf16x8 af[2][2], bf[2][2];
#pragma unroll
    for (int m=0;m<2;m++){
      const int ar_ = wr*32 + m*16 + fr;
#pragma unroll
      for (int ks=0;ks<2;ks++)
        af[m][ks] = *(const bf16x8*)&As[ar_*64 + (((ks*4+fq) ^ (ar_&7))*8)];
    }
#pragma unroll
    for (int n=0;n<2;n++){
      const int br_ = wc*32 + n*16 + fr;
#pragma unroll
      for (int ks=0;ks<2;ks++)
        bf[n][ks] = *(const bf16x8*)&Bs[br_*64 + (((ks*4+fq) ^ (br_&7))*8)];
    }
#pragma unroll
    for (int m=0;m<2;m++)
#pragma unroll
      for (int n=0;n<2;n++)
#pragma unroll
        for (int ks=0;ks<2;ks++)
          acc[m][n] = __builtin_amdgcn_mfma_f32_16x16x32_bf16(af[m][ks], bf[n][ks], acc[m][n], 0,0,0);
    __syncthreads();
  }

  if (!isV){
    const int which = bx >> 1;
    const int n0 = (bx & 1) * 64;
    const float* bb = which ? b2 : b1;
    const float al = which ? a2[0] : a1[0];
#pragma unroll
    for (int m=0;m<2;m++){
#pragma unroll
      for (int n=0;n<2;n++){
        const int c = n0 + wc*32 + n*16 + fr;
        const float bias = bb[c];
#pragma unroll
        for (int reg=0;reg<4;reg++){
          const size_t r = (size_t)(m0 + wr*32 + m*16 + fq*4 + reg);
          float u = acc[m][n][reg] + bias;
          u = u >= 0.f ? u : al*u;
          unsigned short h = bf16rn(u);
          if (which == 0){         // e1x: [h | l]
            e1x[r*256 + c] = h;
            e1x[r*256 + 128 + c] = bf16rn(u - bf16tof(h));
          } else {                 // e2x: [h]
            e2x[r*128 + c] = h;
          }
        }
      }
    }
  } else {
    const int n0 = (bx - 4) * 64;
    const float al = aa[0];
#pragma unroll
    for (int m=0;m<2;m++){
#pragma unroll
      for (int n=0;n<2;n++){
        const int c = n0 + wc*32 + n*16 + fr;
        const float bias = ba[c];
#pragma unroll
        for (int reg=0;reg<4;reg++){
          const size_t r = (size_t)(m0 + wr*32 + m*16 + fq*4 + reg);
          float u = acc[m][n][reg] + bias;
          Vf[r*CCH + c] = u >= 0.f ? u : al*u;
        }
      }
    }
  }
}

// ---- QK^T 128x128: (A_h + A_l)·B over K=128 in 2 steps of 64 ----
// Per step stages {A_h, A_l, B} slices (48 KB LDS), 64 MFMA/wave; barriers 2x2.
// S16 per tile (z,by,bx), 16384 elems: idx = (g*128 + c_l)*4 + (row&3), g=rl>>2.
__global__ __launch_bounds__(256) void qk_mfma(
    const unsigned short* __restrict__ e1base, const unsigned short* __restrict__ e2base,
    _Float16* __restrict__ S16, float* __restrict__ Mg)
{
  __shared__ __align__(16) short Ah[128*64];   // 16 KB (scratch after loop)
  __shared__ __align__(16) short Al[128*64];   // 16 KB
  __shared__ __align__(16) short Bsh[128*64];  // 16 KB
  const int t = threadIdx.x;
  const int bid = (blockIdx.z * 32 + blockIdx.y) * 32 + blockIdx.x;
  const int W = (bid & 7) * 512 + (bid >> 3);
  const int bx = W & 31, by = (W >> 5) & 31, z = W >> 10;
  const int m0 = by*128, n0 = bx*128;
  const int wid = t>>6, lane = t&63;
  const int wr = wid>>1, wc = wid&1;
  const int fr = lane&15, fq = lane>>4;
  const int r32 = t>>3, seg = t&7;

  const unsigned short* ap = e1base + (size_t)z*NN*256 + (size_t)m0*256;
  const unsigned short* bp = e2base + (size_t)z*NN*128 + (size_t)n0*128;

  f32x4 acc[4][4];
#pragma unroll
  for (int m=0;m<4;m++)
#pragma unroll
    for (int n=0;n<4;n++) acc[m][n] = (f32x4){0.f,0.f,0.f,0.f};

#pragma unroll
  for (int s=0;s<2;s++){
    const int kk = s*64;
#pragma unroll
    for (int i=0;i<4;i++){
      const int rowL = r32 + i*32;
      const int sw = (seg ^ (rowL & 7)) * 8;
      gl_lds16(ap + (size_t)rowL*256 + kk + sw,       &Ah[rowL*64 + seg*8]);
      gl_lds16(ap + (size_t)rowL*256 + 128 + kk + sw, &Al[rowL*64 + seg*8]);
      gl_lds16(bp + (size_t)rowL*128 + kk + sw,       &Bsh[rowL*64 + seg*8]);
    }
    __syncthreads();
#pragma unroll
    for (int ks=0;ks<2;ks++){
      bf16x8 bf[4];
#pragma unroll
      for (int n=0;n<4;n++){
        const int br_ = wc*64 + n*16 + fr;
        bf[n] = *(const bf16x8*)&Bsh[br_*64 + (((ks*4+fq) ^ (br_&7))*8)];
      }
#pragma unroll
      for (int m=0;m<4;m++){
        const int ar_ = wr*64 + m*16 + fr;
        const int off = ar_*64 + (((ks*4+fq) ^ (ar_&7))*8);
        const bf16x8 ah = *(const bf16x8*)&Ah[off];
        const bf16x8 al = *(const bf16x8*)&Al[off];
#pragma unroll
        for (int n=0;n<4;n++){
          acc[m][n] = __builtin_amdgcn_mfma_f32_16x16x32_bf16(ah, bf[n], acc[m][n], 0,0,0);
          acc[m][n] = __builtin_amdgcn_mfma_f32_16x16x32_bf16(al, bf[n], acc[m][n], 0,0,0);
        }
      }
    }
    __syncthreads();
  }

  // scratch in Ah (dead after K-loop; barrier-separated)
  float* Mh2 = (float*)Ah;           // 256 floats
  float* Mc  = (float*)Ah + 256;     // 128 floats

  // per-row half-tile max -> combine
#pragma unroll
  for (int m=0;m<4;m++){
#pragma unroll
    for (int reg=0;reg<4;reg++){
      float mm = fmaxf(fmaxf(acc[m][0][reg],acc[m][1][reg]),
                       fmaxf(acc[m][2][reg],acc[m][3][reg]));
#pragma unroll
      for (int o=1;o<16;o<<=1) mm = fmaxf(mm, __shfl_xor(mm, o));
      if (fr == 0) Mh2[(wr*64 + m*16 + fq*4 + reg)*2 + wc] = mm;
    }
  }
  __syncthreads();
  if (t < 128){
    const float vmax = fmaxf(Mh2[t*2+0], Mh2[t*2+1]);
    Mc[t] = vmax;
    Mg[((size_t)z*NN + m0 + t)*32 + bx] = vmax;
  }
  __syncthreads();

  // reg-packed fp16-delta stores: 8B per (m,n)
  _Float16* Sb = S16 + ((size_t)((z*32 + by)*32 + bx))*16384;
#pragma unroll
  for (int m=0;m<4;m++){
    const int g = wr*16 + m*4 + fq;
    const float4 tmv = *(const float4*)&Mc[g*4];
#pragma unroll
    for (int n=0;n<4;n++){
      const int c_l = wc*64 + n*16 + fr;
      uint2 w2;
      w2.x = pkh2(acc[m][n][0] - tmv.x, acc[m][n][1] - tmv.y);
      w2.y = pkh2(acc[m][n][2] - tmv.z, acc[m][n][3] - tmv.w);
      *(uint2*)&Sb[((size_t)g*128 + c_l)*4] = w2;
    }
  }
}

// ---- selective sparsemax + sparse PV over packed fp16-delta S ----
__global__ __launch_bounds__(256) void spv2(
    const _Float16* __restrict__ S16, const float* __restrict__ Mg,
    const float* __restrict__ V, const float* __restrict__ xr,
    float* __restrict__ out)
{
  __shared__ float lv[4][CAP];
  __shared__ int   li[4][CAP];
  const int t = threadIdx.x, wid = t>>6, lane = t&63;
  const int row = blockIdx.x*4 + wid;      // 0..16383
  const int z = row >> 12;
  const int rr = row & (NN-1);
  const int by = rr >> 7, g = (rr & 127) >> 2, reg = rr & 3;
  const _Float16* tbase = S16 + ((size_t)((z*32 + by)*32))*16384 + (size_t)g*512 + reg;
  const float* mrow = Mg + (size_t)row*32;

  // row max from tile maxes
  float mv = (lane < 32) ? mrow[lane] : -1e30f;
#pragma unroll
  for (int o=32;o;o>>=1) mv = fmaxf(mv, __shfl_xor(mv, o));
  const float th = mv - 1.0f;
  const bool q = (lane < 32) && (mrow[lane] > th);
  const unsigned long long qm = __ballot(q);

  // collect candidates {s > th} from qualifying tiles (s = tilemax + delta)
  int cntw = 0;
  {
    unsigned long long rem = qm;
    while (rem){
      const int tile = __ffsll(rem) - 1; rem &= rem - 1;
      const float tm = mrow[tile];
      const _Float16* tp = tbase + (size_t)tile*16384;
      const float s0 = tm + (float)tp[(lane*2)*4];
      const float s1 = tm + (float)tp[(lane*2+1)*4];
      const bool c0 = s0 > th;
      unsigned long long b0 = __ballot(c0);
      int p0 = cntw + __popcll(b0 & ((1ULL<<lane)-1ULL));
      if (c0 && p0 < CAP){ lv[wid][p0] = s0; li[wid][p0] = tile*128 + lane*2; }
      cntw += __popcll(b0);
      const bool c1 = s1 > th;
      unsigned long long b1 = __ballot(c1);
      int p1 = cntw + __popcll(b1 & ((1ULL<<lane)-1ULL));
      if (c1 && p1 < CAP){ lv[wid][p1] = s1; li[wid][p1] = tile*128 + lane*2 + 1; }
      cntw += __popcll(b1);
    }
  }
  const bool ovf = cntw > CAP;

  float tau = th;
  int k = -1;
  if (!ovf){
    float ev[4]; int ei[4];
#pragma unroll
    for (int j=0;j<4;j++){
      const int qq = j*64 + lane;
      if (qq < cntw){ ev[j] = lv[wid][qq]; ei[j] = li[wid][qq]; }
      else          { ev[j] = -1e30f; ei[j] = 0; }
    }
    int prev = -1;
    for (int it=0; it<64; ++it){
      float s = 0.f; int kk = 0;
#pragma unroll
      for (int j=0;j<4;j++) if (ev[j] > tau){ s += ev[j]; kk++; }
#pragma unroll
      for (int o=32;o;o>>=1){ s += __shfl_xor(s,o); kk += __shfl_xor(kk,o); }
      const float tn = (s - 1.f)/(float)kk;
      if (kk == prev) break;
      prev = kk; tau = tn;
    }
    // compact positives (p, idx)
    int k2 = 0;
#pragma unroll
    for (int j=0;j<4;j++){
      const int qq = j*64 + lane;
      const float p = ev[j] - tau;
      const bool nz = (qq < cntw) && (p > 0.f);
      unsigned long long b = __ballot(nz);
      const int pos = k2 + __popcll(b & ((1ULL<<lane)-1ULL));
      if (nz){ lv[wid][pos] = p; li[wid][pos] = ei[j]; }
      k2 += __popcll(b);
    }
    k = k2;
  } else {
    // exact fallback: streaming Michelot over the full reconstructed row
    int prev = -1;
    for (int it=0; it<64; ++it){
      float s = 0.f; int kk = 0;
      for (int tile=0; tile<32; ++tile){
        const float tm = mrow[tile];
        const _Float16* tp = tbase + (size_t)tile*16384;
        const float s0 = tm + (float)tp[(lane*2)*4];
        const float s1 = tm + (float)tp[(lane*2+1)*4];
        if (s0 > tau){ s += s0; kk++; }
        if (s1 > tau){ s += s1; kk++; }
      }
#pragma unroll
      for (int o=32;o;o>>=1){ s += __shfl_xor(s,o); kk += __shfl_xor(kk,o); }
      const float tn = (s - 1.f)/(float)kk;
      if (kk == prev) break;
      prev = kk; tau = tn;
    }
  }

  // sparse PV + residual: lane owns channels lane*4..+3
  const float* Vb = V + ((size_t)z << 12) * CCH;
  float4 a = *(const float4*)&xr[(size_t)row*CCH + lane*4];
  if (k >= 0){
    for (int qq=0; qq<k; ++qq){
      const float p = lv[wid][qq];
      const int ix = li[wid][qq];
      const float4 vv = *(const float4*)&Vb[(size_t)ix*CCH + lane*4];
      a.x = fmaf(p, vv.x, a.x); a.y = fmaf(p, vv.y, a.y);
      a.z = fmaf(p, vv.z, a.z); a.w = fmaf(p, vv.w, a.w);
    }
  } else {
    unsigned long long rem = qm;
    while (rem){
      const int tile = __ffsll(rem) - 1; rem &= rem - 1;
      const float tm = mrow[tile];
      const _Float16* tp = tbase + (size_t)tile*16384;
      const float s0 = tm + (float)tp[(lane*2)*4];
      const float s1 = tm + (float)tp[(lane*2+1)*4];
      int base = 0;
      const bool c0 = s0 > tau;
      unsigned long long b0 = __ballot(c0);
      int p0 = __popcll(b0 & ((1ULL<<lane)-1ULL));
      if (c0){ lv[wid][p0] = s0 - tau; li[wid][p0] = tile*128 + lane*2; }
      base = __popcll(b0);
      const bool c1 = s1 > tau;
      unsigned long long b1 = __ballot(c1);
      int p1 = base + __popcll(b1 & ((1ULL<<lane)-1ULL));
      if (c1){ lv[wid][p1] = s1 - tau; li[wid][p1] = tile*128 + lane*2 + 1; }
      base += __popcll(b1);
      for (int qq=0; qq<base; ++qq){
        const float p = lv[wid][qq];
        const int ix = li[wid][qq];
        const float4 vv = *(const float4*)&Vb[(size_t)ix*CCH + lane*4];
        a.x = fmaf(p, vv.x, a.x); a.y = fmaf(p, vv.y, a.y);
        a.z = fmaf(p, vv.z, a.z); a.w = fmaf(p, vv.w, a.w);
      }
    }
  }
  *(float4*)&out[(size_t)row*CCH + lane*4] = a;
}

extern "C" void kernel_launch(void* const* d_in, const int* in_sizes, int n_in,
                              void* d_out, int out_size, void* d_ws, size_t ws_size,
                              hipStream_t stream) {
  const float* x  = (const float*)d_in[0];
  const float* W1 = (const float*)d_in[1];
  const float* b1 = (const float*)d_in[2];
  const float* a1 = (const float*)d_in[3];
  const float* W2 = (const float*)d_in[4];
  const float* b2 = (const float*)d_in[5];
  const float* a2 = (const float*)d_in[6];
  const float* Wa = (const float*)d_in[7];
  const float* ba = (const float*)d_in[8];
  const float* aa = (const float*)d_in[9];
  float* out = (float*)d_out;

  // ws: xs 25.2MB | Wt 0.8MB | e1x 8.4MB | e2x 4.2MB | V 16.8MB | S16 134MB ~ 190MB
  unsigned short* xs  = (unsigned short*)d_ws;
  unsigned short* Wt  = xs  + (size_t)16384*768;
  unsigned short* e1x = Wt  + (size_t)512*768;
  unsigned short* e2x = e1x + (size_t)16384*256;
  float* Vf = (float*)(e2x + (size_t)16384*128);
  _Float16* S16 = (_Float16*)(Vf + (size_t)BB*NN*CCH);
  float* Mg = (float*)xs;   // xs dead after proj_mfma; tile maxes 2MB

  dim3 blk(256);
  prep_x<<<dim3(2048,1,1), blk, 0, stream>>>(x, xs);
  prep_w<<<dim3(512,1,1), blk, 0, stream>>>(W1, W2, Wa, Wt);
  proj_mfma<<<dim3(8,256,1), blk, 0, stream>>>(xs, Wt, b1,a1, b2,a2, ba,aa,
                                               e1x, e2x, Vf);
  qk_mfma<<<dim3(32,32,4), blk, 0, stream>>>(e1x, e2x, S16, Mg);
  spv2<<<dim3(4096,1,1), blk, 0, stream>>>(S16, Mg, Vf, x, out);
}

// Round 28
// 112.135 us; speedup vs baseline: 1.7157x; 1.0296x over previous
//
#include <hip/hip_runtime.h>
#include <cstdint>

#define BB 4
#define NN 4096
#define CCH 256
#define CAP 256

typedef __attribute__((ext_vector_type(8))) short bf16x8;
typedef __attribute__((ext_vector_type(4))) float f32x4;

__device__ __forceinline__ unsigned short bf16rn(float f){
  unsigned u = __float_as_uint(f);
  unsigned r = u + 0x7FFFu + ((u>>16)&1u);
  return (unsigned short)(r>>16);
}
__device__ __forceinline__ float bf16tof(unsigned short h){
  return __uint_as_float(((unsigned)h)<<16);
}
__device__ __forceinline__ void gl_lds16(const void* g, void* l){
  __builtin_amdgcn_global_load_lds(
    (const __attribute__((address_space(1))) void*)g,
    (__attribute__((address_space(3))) void*)l, 16, 0, 0);
}
__device__ __forceinline__ unsigned pkh2(float a, float b){
  unsigned short u0 = __builtin_bit_cast(unsigned short, (_Float16)a);
  unsigned short u1 = __builtin_bit_cast(unsigned short, (_Float16)b);
  return (unsigned)u0 | ((unsigned)u1 << 16);
}

// ---- prep: split x -> xs [16384][512] bf16 (hi | lo) ----
__global__ __launch_bounds__(256) void prep_x(
    const float* __restrict__ x, unsigned short* __restrict__ xs)
{
  const int stride = gridDim.x * 256;
  for (int idx = blockIdx.x*256 + threadIdx.x; idx < 16384*64; idx += stride){
    const int r = idx >> 6, c4 = (idx & 63) * 4;
    float4 u = *(const float4*)(x + (size_t)r*256 + c4);
    ushort4 h, l;
    h.x=bf16rn(u.x); l.x=bf16rn(u.x - bf16tof(h.x));
    h.y=bf16rn(u.y); l.y=bf16rn(u.y - bf16tof(h.y));
    h.z=bf16rn(u.z); l.z=bf16rn(u.z - bf16tof(h.z));
    h.w=bf16rn(u.w); l.w=bf16rn(u.w - bf16tof(h.w));
    unsigned short* row = xs + (size_t)r*512;
    *(ushort4*)(row + c4)       = h;
    *(ushort4*)(row + 256 + c4) = l;
  }
}

// ---- prep: weights -> Wt [512][512] bf16 (hi | lo), rows = output cols ----
__global__ __launch_bounds__(256) void prep_w(
    const float* __restrict__ W1, const float* __restrict__ W2,
    const float* __restrict__ Wa, unsigned short* __restrict__ Wt)
{
  const int n = blockIdx.x;      // 512
  const int k = threadIdx.x;     // 256
  float w = (n < 128) ? W1[(size_t)k*128 + n]
          : (n < 256) ? W2[(size_t)k*128 + (n-128)]
                      : Wa[(size_t)k*256 + (n-256)];
  unsigned short h = bf16rn(w);
  unsigned short l = bf16rn(w - bf16tof(h));
  unsigned short* row = Wt + (size_t)n*512;
  row[k] = h; row[256+k] = l;
}

// ---- fused projection GEMM: 64x64 tiles (8 bx x 256 by), XCD-swizzled ----
// e-tiles: phase1 (x_h + x_l)·W_h (4 steps, shared B), phase2 x_h·W_l (4 steps).
// V-tiles: x_h·W_h only (4 steps). e1 out [h|l] 256-wide; e2 out [h] 128-wide.
__global__ __launch_bounds__(256) void proj_mfma(
    const unsigned short* __restrict__ xs, const unsigned short* __restrict__ Wt,
    const float* __restrict__ b1, const float* __restrict__ a1,
    const float* __restrict__ b2, const float* __restrict__ a2,
    const float* __restrict__ ba, const float* __restrict__ aa,
    unsigned short* __restrict__ e1x, unsigned short* __restrict__ e2x,
    float* __restrict__ Vf)
{
  __shared__ __align__(16) short Ah[64*64];   // 8 KB
  __shared__ __align__(16) short Al[64*64];   // 8 KB
  __shared__ __align__(16) short Bsx[64*64];  // 8 KB
  const int t = threadIdx.x;
  const int bid = blockIdx.y * 8 + blockIdx.x;
  const int W = (bid & 7) * 256 + (bid >> 3);
  const int bx = W & 7, by = W >> 3;
  const int m0 = by*64;
  const int wid = t>>6, lane = t&63;
  const int wr = wid>>1, wc = wid&1;
  const int fr = lane&15, fq = lane>>4;
  const int r32 = t>>3, seg = t&7;

  const bool isV = bx >= 4;
  const int wrow = isV ? (256 + (bx-4)*64) : ((bx>>1)*128 + (bx&1)*64);
  const unsigned short* ap = xs + (size_t)m0*512;
  const unsigned short* bp = Wt + (size_t)wrow*512;

  f32x4 acc[2][2];
#pragma unroll
  for (int m=0;m<2;m++)
#pragma unroll
    for (int n=0;n<2;n++) acc[m][n] = (f32x4){0.f,0.f,0.f,0.f};

  if (!isV){
    // phase 1: (x_h + x_l) · W_h over K=256
#pragma unroll
    for (int s=0;s<4;s++){
      const int kk = s*64;
#pragma unroll
      for (int i=0;i<2;i++){
        const int rowL = r32 + i*32;
        const int sw = (seg ^ (rowL & 7)) * 8;
        gl_lds16(ap + (size_t)rowL*512 + kk + sw,       &Ah[rowL*64 + seg*8]);
        gl_lds16(ap + (size_t)rowL*512 + 256 + kk + sw, &Al[rowL*64 + seg*8]);
        gl_lds16(bp + (size_t)rowL*512 + kk + sw,       &Bsx[rowL*64 + seg*8]);
      }
      __syncthreads();
#pragma unroll
      for (int ks=0;ks<2;ks++){
        bf16x8 bf[2];
#pragma unroll
        for (int n=0;n<2;n++){
          const int br_ = wc*32 + n*16 + fr;
          bf[n] = *(const bf16x8*)&Bsx[br_*64 + (((ks*4+fq) ^ (br_&7))*8)];
        }
#pragma unroll
        for (int m=0;m<2;m++){
          const int ar_ = wr*32 + m*16 + fr;
          const int off = ar_*64 + (((ks*4+fq) ^ (ar_&7))*8);
          const bf16x8 ah = *(const bf16x8*)&Ah[off];
          const bf16x8 al = *(const bf16x8*)&Al[off];
#pragma unroll
          for (int n=0;n<2;n++){
            acc[m][n] = __builtin_amdgcn_mfma_f32_16x16x32_bf16(ah, bf[n], acc[m][n], 0,0,0);
            acc[m][n] = __builtin_amdgcn_mfma_f32_16x16x32_bf16(al, bf[n], acc[m][n], 0,0,0);
          }
        }
      }
      __syncthreads();
    }
    // phase 2: x_h · W_l over K=256
#pragma unroll
    for (int s=0;s<4;s++){
      const int kk = s*64;
#pragma unroll
      for (int i=0;i<2;i++){
        const int rowL = r32 + i*32;
        const int sw = (seg ^ (rowL & 7)) * 8;
        gl_lds16(ap + (size_t)rowL*512 + kk + sw,       &Ah[rowL*64 + seg*8]);
        gl_lds16(bp + (size_t)rowL*512 + 256 + kk + sw, &Bsx[rowL*64 + seg*8]);
      }
      __syncthreads();
#pragma unroll
      for (int ks=0;ks<2;ks++){
        bf16x8 bf[2];
#pragma unroll
        for (int n=0;n<2;n++){
          const int br_ = wc*32 + n*16 + fr;
          bf[n] = *(const bf16x8*)&Bsx[br_*64 + (((ks*4+fq) ^ (br_&7))*8)];
        }
#pragma unroll
        for (int m=0;m<2;m++){
          const int ar_ = wr*32 + m*16 + fr;
          const bf16x8 ah = *(const bf16x8*)&Ah[ar_*64 + (((ks*4+fq) ^ (ar_&7))*8)];
#pragma unroll
          for (int n=0;n<2;n++)
            acc[m][n] = __builtin_amdgcn_mfma_f32_16x16x32_bf16(ah, bf[n], acc[m][n], 0,0,0);
        }
      }
      __syncthreads();
    }
  } else {
    // V: x_h · W_h only (K=256)
#pragma unroll
    for (int s=0;s<4;s++){
      const int kk = s*64;
#pragma unroll
      for (int i=0;i<2;i++){
        const int rowL = r32 + i*32;
        const int sw = (seg ^ (rowL & 7)) * 8;
        gl_lds16(ap + (size_t)rowL*512 + kk + sw, &Ah[rowL*64 + seg*8]);
        gl_lds16(bp + (size_t)rowL*512 + kk + sw, &Bsx[rowL*64 + seg*8]);
      }
      __syncthreads();
#pragma unroll
      for (int ks=0;ks<2;ks++){
        bf16x8 bf[2];
#pragma unroll
        for (int n=0;n<2;n++){
          const int br_ = wc*32 + n*16 + fr;
          bf[n] = *(const bf16x8*)&Bsx[br_*64 + (((ks*4+fq) ^ (br_&7))*8)];
        }
#pragma unroll
        for (int m=0;m<2;m++){
          const int ar_ = wr*32 + m*16 + fr;
          const bf16x8 ah = *(const bf16x8*)&Ah[ar_*64 + (((ks*4+fq) ^ (ar_&7))*8)];
#pragma unroll
          for (int n=0;n<2;n++)
            acc[m][n] = __builtin_amdgcn_mfma_f32_16x16x32_bf16(ah, bf[n], acc[m][n], 0,0,0);
        }
      }
      __syncthreads();
    }
  }

  if (!isV){
    const int which = bx >> 1;
    const int n0 = (bx & 1) * 64;
    const float* bb = which ? b2 : b1;
    const float al = which ? a2[0] : a1[0];
#pragma unroll
    for (int m=0;m<2;m++){
#pragma unroll
      for (int n=0;n<2;n++){
        const int c = n0 + wc*32 + n*16 + fr;
        const float bias = bb[c];
#pragma unroll
        for (int reg=0;reg<4;reg++){
          const size_t r = (size_t)(m0 + wr*32 + m*16 + fq*4 + reg);
          float u = acc[m][n][reg] + bias;
          u = u >= 0.f ? u : al*u;
          unsigned short h = bf16rn(u);
          if (which == 0){         // e1x: [h | l]
            e1x[r*256 + c] = h;
            e1x[r*256 + 128 + c] = bf16rn(u - bf16tof(h));
          } else {                 // e2x: [h]
            e2x[r*128 + c] = h;
          }
        }
      }
    }
  } else {
    const int n0 = (bx - 4) * 64;
    const float al = aa[0];
#pragma unroll
    for (int m=0;m<2;m++){
#pragma unroll
      for (int n=0;n<2;n++){
        const int c = n0 + wc*32 + n*16 + fr;
        const float bias = ba[c];
#pragma unroll
        for (int reg=0;reg<4;reg++){
          const size_t r = (size_t)(m0 + wr*32 + m*16 + fq*4 + reg);
          float u = acc[m][n][reg] + bias;
          Vf[r*CCH + c] = u >= 0.f ? u : al*u;
        }
      }
    }
  }
}

// ---- QK^T 128x128: (A_h + A_l)·B over K=128 in 2 steps of 64 ----
// Per step stages {A_h, A_l, B} slices (48 KB LDS), 64 MFMA/wave; barriers 2x2.
// S16 per tile (z,by,bx), 16384 elems: idx = (g*128 + c_l)*4 + (row&3), g=rl>>2.
__global__ __launch_bounds__(256) void qk_mfma(
    const unsigned short* __restrict__ e1base, const unsigned short* __restrict__ e2base,
    _Float16* __restrict__ S16, float* __restrict__ Mg)
{
  __shared__ __align__(16) short Ah[128*64];   // 16 KB (scratch after loop)
  __shared__ __align__(16) short Al[128*64];   // 16 KB
  __shared__ __align__(16) short Bsh[128*64];  // 16 KB
  const int t = threadIdx.x;
  const int bid = (blockIdx.z * 32 + blockIdx.y) * 32 + blockIdx.x;
  const int W = (bid & 7) * 512 + (bid >> 3);
  const int bx = W & 31, by = (W >> 5) & 31, z = W >> 10;
  const int m0 = by*128, n0 = bx*128;
  const int wid = t>>6, lane = t&63;
  const int wr = wid>>1, wc = wid&1;
  const int fr = lane&15, fq = lane>>4;
  const int r32 = t>>3, seg = t&7;

  const unsigned short* ap = e1base + (size_t)z*NN*256 + (size_t)m0*256;
  const unsigned short* bp = e2base + (size_t)z*NN*128 + (size_t)n0*128;

  f32x4 acc[4][4];
#pragma unroll
  for (int m=0;m<4;m++)
#pragma unroll
    for (int n=0;n<4;n++) acc[m][n] = (f32x4){0.f,0.f,0.f,0.f};

#pragma unroll
  for (int s=0;s<2;s++){
    const int kk = s*64;
#pragma unroll
    for (int i=0;i<4;i++){
      const int rowL = r32 + i*32;
      const int sw = (seg ^ (rowL & 7)) * 8;
      gl_lds16(ap + (size_t)rowL*256 + kk + sw,       &Ah[rowL*64 + seg*8]);
      gl_lds16(ap + (size_t)rowL*256 + 128 + kk + sw, &Al[rowL*64 + seg*8]);
      gl_lds16(bp + (size_t)rowL*128 + kk + sw,       &Bsh[rowL*64 + seg*8]);
    }
    __syncthreads();
#pragma unroll
    for (int ks=0;ks<2;ks++){
      bf16x8 bf[4];
#pragma unroll
      for (int n=0;n<4;n++){
        const int br_ = wc*64 + n*16 + fr;
        bf[n] = *(const bf16x8*)&Bsh[br_*64 + (((ks*4+fq) ^ (br_&7))*8)];
      }
#pragma unroll
      for (int m=0;m<4;m++){
        const int ar_ = wr*64 + m*16 + fr;
        const int off = ar_*64 + (((ks*4+fq) ^ (ar_&7))*8);
        const bf16x8 ah = *(const bf16x8*)&Ah[off];
        const bf16x8 al = *(const bf16x8*)&Al[off];
#pragma unroll
        for (int n=0;n<4;n++){
          acc[m][n] = __builtin_amdgcn_mfma_f32_16x16x32_bf16(ah, bf[n], acc[m][n], 0,0,0);
          acc[m][n] = __builtin_amdgcn_mfma_f32_16x16x32_bf16(al, bf[n], acc[m][n], 0,0,0);
        }
      }
    }
    __syncthreads();
  }

  // scratch in Ah (dead after K-loop; barrier-separated)
  float* Mh2 = (float*)Ah;           // 256 floats
  float* Mc  = (float*)Ah + 256;     // 128 floats

  // per-row half-tile max -> combine
#pragma unroll
  for (int m=0;m<4;m++){
#pragma unroll
    for (int reg=0;reg<4;reg++){
      float mm = fmaxf(fmaxf(acc[m][0][reg],acc[m][1][reg]),
                       fmaxf(acc[m][2][reg],acc[m][3][reg]));
#pragma unroll
      for (int o=1;o<16;o<<=1) mm = fmaxf(mm, __shfl_xor(mm, o));
      if (fr == 0) Mh2[(wr*64 + m*16 + fq*4 + reg)*2 + wc] = mm;
    }
  }
  __syncthreads();
  if (t < 128){
    const float vmax = fmaxf(Mh2[t*2+0], Mh2[t*2+1]);
    Mc[t] = vmax;
    Mg[((size_t)z*NN + m0 + t)*32 + bx] = vmax;
  }
  __syncthreads();

  // reg-packed fp16-delta stores: 8B per (m,n)
  _Float16* Sb = S16 + ((size_t)((z*32 + by)*32 + bx))*16384;
#pragma unroll
  for (int m=0;m<4;m++){
    const int g = wr*16 + m*4 + fq;
    const float4 tmv = *(const float4*)&Mc[g*4];
#pragma unroll
    for (int n=0;n<4;n++){
      const int c_l = wc*64 + n*16 + fr;
      uint2 w2;
      w2.x = pkh2(acc[m][n][0] - tmv.x, acc[m][n][1] - tmv.y);
      w2.y = pkh2(acc[m][n][2] - tmv.z, acc[m][n][3] - tmv.w);
      *(uint2*)&Sb[((size_t)g*128 + c_l)*4] = w2;
    }
  }
}

// ---- selective sparsemax + sparse PV over packed fp16-delta S ----
__global__ __launch_bounds__(256) void spv2(
    const _Float16* __restrict__ S16, const float* __restrict__ Mg,
    const float* __restrict__ V, const float* __restrict__ xr,
    float* __restrict__ out)
{
  __shared__ float lv[4][CAP];
  __shared__ int   li[4][CAP];
  const int t = threadIdx.x, wid = t>>6, lane = t&63;
  const int row = blockIdx.x*4 + wid;      // 0..16383
  const int z = row >> 12;
  const int rr = row & (NN-1);
  const int by = rr >> 7, g = (rr & 127) >> 2, reg = rr & 3;
  const _Float16* tbase = S16 + ((size_t)((z*32 + by)*32))*16384 + (size_t)g*512 + reg;
  const float* mrow = Mg + (size_t)row*32;

  // row max from tile maxes
  float mv = (lane < 32) ? mrow[lane] : -1e30f;
#pragma unroll
  for (int o=32;o;o>>=1) mv = fmaxf(mv, __shfl_xor(mv, o));
  const float th = mv - 1.0f;
  const bool q = (lane < 32) && (mrow[lane] > th);
  const unsigned long long qm = __ballot(q);

  // collect candidates {s > th} from qualifying tiles (s = tilemax + delta)
  int cntw = 0;
  {
    unsigned long long rem = qm;
    while (rem){
      const int tile = __ffsll(rem) - 1; rem &= rem - 1;
      const float tm = mrow[tile];
      const _Float16* tp = tbase + (size_t)tile*16384;
      const float s0 = tm + (float)tp[(lane*2)*4];
      const float s1 = tm + (float)tp[(lane*2+1)*4];
      const bool c0 = s0 > th;
      unsigned long long b0 = __ballot(c0);
      int p0 = cntw + __popcll(b0 & ((1ULL<<lane)-1ULL));
      if (c0 && p0 < CAP){ lv[wid][p0] = s0; li[wid][p0] = tile*128 + lane*2; }
      cntw += __popcll(b0);
      const bool c1 = s1 > th;
      unsigned long long b1 = __ballot(c1);
      int p1 = cntw + __popcll(b1 & ((1ULL<<lane)-1ULL));
      if (c1 && p1 < CAP){ lv[wid][p1] = s1; li[wid][p1] = tile*128 + lane*2 + 1; }
      cntw += __popcll(b1);
    }
  }
  const bool ovf = cntw > CAP;

  float tau = th;
  int k = -1;
  if (!ovf){
    float ev[4]; int ei[4];
#pragma unroll
    for (int j=0;j<4;j++){
      const int qq = j*64 + lane;
      if (qq < cntw){ ev[j] = lv[wid][qq]; ei[j] = li[wid][qq]; }
      else          { ev[j] = -1e30f; ei[j] = 0; }
    }
    int prev = -1;
    for (int it=0; it<64; ++it){
      float s = 0.f; int kk = 0;
#pragma unroll
      for (int j=0;j<4;j++) if (ev[j] > tau){ s += ev[j]; kk++; }
#pragma unroll
      for (int o=32;o;o>>=1){ s += __shfl_xor(s,o); kk += __shfl_xor(kk,o); }
      const float tn = (s - 1.f)/(float)kk;
      if (kk == prev) break;
      prev = kk; tau = tn;
    }
    // compact positives (p, idx)
    int k2 = 0;
#pragma unroll
    for (int j=0;j<4;j++){
      const int qq = j*64 + lane;
      const float p = ev[j] - tau;
      const bool nz = (qq < cntw) && (p > 0.f);
      unsigned long long b = __ballot(nz);
      const int pos = k2 + __popcll(b & ((1ULL<<lane)-1ULL));
      if (nz){ lv[wid][pos] = p; li[wid][pos] = ei[j]; }
      k2 += __popcll(b);
    }
    k = k2;
  } else {
    // exact fallback: streaming Michelot over the full reconstructed row
    int prev = -1;
    for (int it=0; it<64; ++it){
      float s = 0.f; int kk = 0;
      for (int tile=0; tile<32; ++tile){
        const float tm = mrow[tile];
        const _Float16* tp = tbase + (size_t)tile*16384;
        const float s0 = tm + (float)tp[(lane*2)*4];
        const float s1 = tm + (float)tp[(lane*2+1)*4];
        if (s0 > tau){ s += s0; kk++; }
        if (s1 > tau){ s += s1; kk++; }
      }
#pragma unroll
      for (int o=32;o;o>>=1){ s += __shfl_xor(s,o); kk += __shfl_xor(kk,o); }
      const float tn = (s - 1.f)/(float)kk;
      if (kk == prev) break;
      prev = kk; tau = tn;
    }
  }

  // sparse PV + residual: lane owns channels lane*4..+3
  const float* Vb = V + ((size_t)z << 12) * CCH;
  float4 a = *(const float4*)&xr[(size_t)row*CCH + lane*4];
  if (k >= 0){
    for (int qq=0; qq<k; ++qq){
      const float p = lv[wid][qq];
      const int ix = li[wid][qq];
      const float4 vv = *(const float4*)&Vb[(size_t)ix*CCH + lane*4];
      a.x = fmaf(p, vv.x, a.x); a.y = fmaf(p, vv.y, a.y);
      a.z = fmaf(p, vv.z, a.z); a.w = fmaf(p, vv.w, a.w);
    }
  } else {
    unsigned long long rem = qm;
    while (rem){
      const int tile = __ffsll(rem) - 1; rem &= rem - 1;
      const float tm = mrow[tile];
      const _Float16* tp = tbase + (size_t)tile*16384;
      const float s0 = tm + (float)tp[(lane*2)*4];
      const float s1 = tm + (float)tp[(lane*2+1)*4];
      int base = 0;
      const bool c0 = s0 > tau;
      unsigned long long b0 = __ballot(c0);
      int p0 = __popcll(b0 & ((1ULL<<lane)-1ULL));
      if (c0){ lv[wid][p0] = s0 - tau; li[wid][p0] = tile*128 + lane*2; }
      base = __popcll(b0);
      const bool c1 = s1 > tau;
      unsigned long long b1 = __ballot(c1);
      int p1 = base + __popcll(b1 & ((1ULL<<lane)-1ULL));
      if (c1){ lv[wid][p1] = s1 - tau; li[wid][p1] = tile*128 + lane*2 + 1; }
      base += __popcll(b1);
      for (int qq=0; qq<base; ++qq){
        const float p = lv[wid][qq];
        const int ix = li[wid][qq];
        const float4 vv = *(const float4*)&Vb[(size_t)ix*CCH + lane*4];
        a.x = fmaf(p, vv.x, a.x); a.y = fmaf(p, vv.y, a.y);
        a.z = fmaf(p, vv.z, a.z); a.w = fmaf(p, vv.w, a.w);
      }
    }
  }
  *(float4*)&out[(size_t)row*CCH + lane*4] = a;
}

extern "C" void kernel_launch(void* const* d_in, const int* in_sizes, int n_in,
                              void* d_out, int out_size, void* d_ws, size_t ws_size,
                              hipStream_t stream) {
  const float* x  = (const float*)d_in[0];
  const float* W1 = (const float*)d_in[1];
  const float* b1 = (const float*)d_in[2];
  const float* a1 = (const float*)d_in[3];
  const float* W2 = (const float*)d_in[4];
  const float* b2 = (const float*)d_in[5];
  const float* a2 = (const float*)d_in[6];
  const float* Wa = (const float*)d_in[7];
  const float* ba = (const float*)d_in[8];
  const float* aa = (const float*)d_in[9];
  float* out = (float*)d_out;

  // ws: xs 16.8MB | Wt 0.5MB | e1x 8.4MB | e2x 4.2MB | V 16.8MB | S16 134MB ~ 181MB
  unsigned short* xs  = (unsigned short*)d_ws;
  unsigned short* Wt  = xs  + (size_t)16384*512;
  unsigned short* e1x = Wt  + (size_t)512*512;
  unsigned short* e2x = e1x + (size_t)16384*256;
  float* Vf = (float*)(e2x + (size_t)16384*128);
  _Float16* S16 = (_Float16*)(Vf + (size_t)BB*NN*CCH);
  float* Mg = (float*)xs;   // xs dead after proj_mfma; tile maxes 2MB

  dim3 blk(256);
  prep_x<<<dim3(2048,1,1), blk, 0, stream>>>(x, xs);
  prep_w<<<dim3(512,1,1), blk, 0, stream>>>(W1, W2, Wa, Wt);
  proj_mfma<<<dim3(8,256,1), blk, 0, stream>>>(xs, Wt, b1,a1, b2,a2, ba,aa,
                                               e1x, e2x, Vf);
  qk_mfma<<<dim3(32,32,4), blk, 0, stream>>>(e1x, e2x, S16, Mg);
  spv2<<<dim3(4096,1,1), blk, 0, stream>>>(S16, Mg, Vf, x, out);
}